// Round 1
// baseline (86.988 us; speedup 1.0000x reference)
//
#include <hip/hip_runtime.h>
#include <math.h>

#define K 1024
#define SAMPLES 4096
#define S (SAMPLES - 1)

// irregular_gauss: std = exp(x<=mean ? low : high); exp(-0.5*((x-mean)/std)^2)
__device__ __forceinline__ float ig(float x, float mean, float lo, float hi) {
    float sel = (x <= mean) ? lo : hi;
    float z = (x - mean) * __expf(-sel);   // (x-mean)/exp(sel)
    return __expf(-0.5f * z * z);
}

__device__ __forceinline__ float block_reduce256(float v, float* sm) {
    #pragma unroll
    for (int o = 32; o > 0; o >>= 1) v += __shfl_down(v, o, 64);
    int lane = threadIdx.x & 63, w = threadIdx.x >> 6;
    if (lane == 0) sm[w] = v;
    __syncthreads();
    float r = 0.f;
    if (threadIdx.x == 0) r = sm[0] + sm[1] + sm[2] + sm[3];
    __syncthreads();
    return r;
}

// Kernel 1: per knot k, A[k] = sum_s smear[k,s]; R[k] = S * smear[k,0]
// Blocks 0..31 additionally zero res/env (2*S contiguous floats) so no
// separate memset dispatch is needed (stream order guarantees completion
// before k_accumulate runs).
__global__ __launch_bounds__(256) void k_smear_sums(
    const float* __restrict__ x, const float* __restrict__ sw,
    const float* __restrict__ km, const float* __restrict__ kl, const float* __restrict__ kh,
    float* __restrict__ A, float* __restrict__ R, float* __restrict__ zero_base)
{
    __shared__ float sm[4];
    int k = blockIdx.x;
    if (k < 32) {
        int idx = k * 256 + threadIdx.x;
        if (idx < 2 * S) zero_base[idx] = 0.f;
    }
    float lower = sw[0], upper = sw[1];
    float xk = x[k];
    float x_step = (upper - lower) * xk * (1.0f / SAMPLES);
    float x_low = (1.0f - lower) * xk;
    float mean = km[k], lo = kl[k], hi = kh[k];
    float sum = 0.f;
    for (int s = threadIdx.x; s < S; s += 256) {
        float g = x_step * ((float)s * (1.0f / SAMPLES)) + x_low;
        sum += ig(g, mean, lo, hi);
    }
    float tot = block_reduce256(sum, sm);
    if (threadIdx.x == 0) {
        A[k] = tot;
        R[k] = (float)S * ig(x_low, mean, lo, hi);  // x_iter[0]==0
    }
}

// Kernel 2: blocks [0,K): row reductions coef1[i], M[i].
//           blocks [K,2K): column reduction colsum[j].
__global__ __launch_bounds__(256) void k_entangle(
    const float* __restrict__ A, const float* __restrict__ R,
    const float* __restrict__ em, const float* __restrict__ el, const float* __restrict__ eh,
    const float* __restrict__ pol,
    float* __restrict__ coef1, float* __restrict__ colsum, float* __restrict__ M)
{
    __shared__ float sm0[4], sm1[4];
    int b = blockIdx.x;
    if (b < K) {
        int i = b;
        float Ai = A[i];
        float c = 0.f, m = 0.f;
        for (int j = threadIdx.x; j < K; j += 256) {
            if (j == i) continue;
            float corr = Ai * A[j] * (1.0f / S);
            float mix = ig(corr, em[j], el[j], eh[j]);
            c += mix * __cosf(pol[j]) * R[j];
            m += mix;
        }
        float ct = block_reduce256(c, sm0);
        float mt = block_reduce256(m, sm1);
        if (threadIdx.x == 0) { coef1[i] = ct; M[i] = mt; }
    } else {
        int j = b - K;
        float Aj = A[j];
        float mean = em[j], lo = el[j], hi = eh[j];
        float cs = 0.f;
        for (int i = threadIdx.x; i < K; i += 256) {
            if (i == j) continue;
            float corr = A[i] * Aj * (1.0f / S);
            cs += R[i] * ig(corr, mean, lo, hi);
        }
        float ct = block_reduce256(cs, sm0);
        if (threadIdx.x == 0) colsum[j] = ct;
    }
}

// Kernel 3: accumulate res[s] = sum_k w_k*smear[k,s], env[s] = sum_k gauss[k,s]
#define SB 16   // ceil(S/256) s-blocks
#define NC 32   // knot chunks
#define KPC (K / NC)
__global__ __launch_bounds__(256) void k_accumulate(
    const float* __restrict__ x, const float* __restrict__ sw,
    const float* __restrict__ km, const float* __restrict__ kl, const float* __restrict__ kh,
    const float* __restrict__ pol,
    const float* __restrict__ coef1, const float* __restrict__ colsum, const float* __restrict__ M,
    float* __restrict__ res, float* __restrict__ env)
{
    int sb = blockIdx.x % SB;
    int kc = blockIdx.x / SB;
    int s = sb * 256 + threadIdx.x;
    if (s >= S) return;
    float xi = (float)s * (1.0f / SAMPLES);
    float lower = sw[0], upper = sw[1];
    float rsum = 0.f, esum = 0.f;
    int k0 = kc * KPC;
    #pragma unroll 4
    for (int k = k0; k < k0 + KPC; ++k) {
        float xk = x[k];
        float x_step = (upper - lower) * xk * (1.0f / SAMPLES);
        float x_low = (1.0f - lower) * xk;
        float smear = ig(x_step * xi + x_low, km[k], kl[k], kh[k]);
        float w = coef1[k] + __sinf(pol[k]) * colsum[k] + (float)(K - 1) - M[k];
        rsum += w * smear;
        float lows = x_low;                      // (1-lower)*x
        float highs = (1.0f + upper) * xk;
        float g = (highs - lows) * xi + lows;
        esum += ig(g, xk, lows, highs);
    }
    atomicAdd(&res[s], rsum);
    atomicAdd(&env[s], esum);
}

// Kernel 4: out[s] = env[s] * res[s]
__global__ __launch_bounds__(256) void k_final(
    const float* __restrict__ res, const float* __restrict__ env, float* __restrict__ out)
{
    int s = blockIdx.x * 256 + threadIdx.x;
    if (s < S) out[s] = env[s] * res[s];
}

extern "C" void kernel_launch(void* const* d_in, const int* in_sizes, int n_in,
                              void* d_out, int out_size, void* d_ws, size_t ws_size,
                              hipStream_t stream)
{
    const float* x   = (const float*)d_in[0];
    const float* sw  = (const float*)d_in[1];  // smear_window [lower, upper]
    const float* km  = (const float*)d_in[2];
    const float* kl  = (const float*)d_in[3];
    const float* kh  = (const float*)d_in[4];
    const float* em  = (const float*)d_in[5];
    const float* el  = (const float*)d_in[6];
    const float* eh  = (const float*)d_in[7];
    const float* pol = (const float*)d_in[8];
    float* out = (float*)d_out;

    float* A      = (float*)d_ws;
    float* R      = A + K;
    float* coef1  = R + K;
    float* colsum = coef1 + K;
    float* M      = colsum + K;
    float* res    = M + K;        // [S]
    float* env    = res + S;      // [S] (contiguous with res; zeroed by k_smear_sums)

    k_smear_sums<<<K, 256, 0, stream>>>(x, sw, km, kl, kh, A, R, res);
    k_entangle<<<2 * K, 256, 0, stream>>>(A, R, em, el, eh, pol, coef1, colsum, M);
    k_accumulate<<<SB * NC, 256, 0, stream>>>(x, sw, km, kl, kh, pol, coef1, colsum, M, res, env);
    k_final<<<16, 256, 0, stream>>>(res, env, out);
}